// Round 1
// baseline (249.719 us; speedup 1.0000x reference)
//
#include <hip/hip_runtime.h>
#include <cmath>

typedef _Float16 half8 __attribute__((ext_vector_type(8)));
typedef float f32x4 __attribute__((ext_vector_type(4)));

#define GLD_LDS16(gptr, lptr)                                                  \
  __builtin_amdgcn_global_load_lds(                                            \
      (const __attribute__((address_space(1))) void*)(gptr),                   \
      (__attribute__((address_space(3))) void*)(lptr), 16, 0, 0)

// ---------------- f32 -> f16 conversion (vectorized, grid-stride) -----------
__global__ void cvt_f32_to_f16(const float* __restrict__ in,
                               _Float16* __restrict__ out, long n) {
  long stride = (long)gridDim.x * blockDim.x * 8;
  for (long i = ((long)blockIdx.x * blockDim.x + threadIdx.x) * 8; i < n;
       i += stride) {
    const float4* p = (const float4*)(in + i);
    float4 a = p[0];
    float4 b = p[1];
    half8 h = {(_Float16)a.x, (_Float16)a.y, (_Float16)a.z, (_Float16)a.w,
               (_Float16)b.x, (_Float16)b.y, (_Float16)b.z, (_Float16)b.w};
    *(half8*)(out + i) = h;
  }
}

// ---------------- GEMM: C[m,n] = sum_k A[m,k]*B[n,k]  (both K-major) --------
// EPI: 0 = acc+bias -> f16 ; 1 = 0.5*tanh(acc+bias) -> f16 ; 2 = acc+bias -> f32
// 128x128 tile, BK=64, 256 threads (4 waves, each computes 64x64),
// global_load_lds width-16 staging, mfma_f32_16x16x32_f16.
template <int EPI>
__global__ __launch_bounds__(256, 2) void gemm_bt(
    const _Float16* __restrict__ A, const _Float16* __restrict__ Bm,
    const float* __restrict__ bias, void* __restrict__ Cout, int M, int N,
    int K) {
  (void)M;
  __shared__ _Float16 As[128 * 64];
  __shared__ _Float16 Bs[128 * 64];

  const int tid = threadIdx.x;
  const int lane = tid & 63;
  const int wave = tid >> 6;
  const int brow = blockIdx.y * 128;  // M tile
  const int bcol = blockIdx.x * 128;  // N tile
  const int wr = (wave >> 1) * 64;    // wave row offset in tile
  const int wc = (wave & 1) * 64;     // wave col offset in tile

  f32x4 acc[4][4];
#pragma unroll
  for (int m = 0; m < 4; m++)
#pragma unroll
    for (int n = 0; n < 4; n++) acc[m][n] = f32x4{0.f, 0.f, 0.f, 0.f};

  // staging decomposition: 256 threads x 16B = 4 KB per issue; 4 issues per
  // 128x64 f16 tile. thread t covers row (i*32 + t/8), cols (t%8)*8..+8.
  const int srow = tid >> 3;        // 0..31
  const int scol = (tid & 7) * 8;   // f16 element offset

  const _Float16* Ag = A + (size_t)brow * K + scol;
  const _Float16* Bg = Bm + (size_t)bcol * K + scol;

  const int frow = lane & 15;        // row/col within 16x16 fragment
  const int fk = (lane >> 4) * 8;    // k offset within 32

  for (int k0 = 0; k0 < K; k0 += 64) {
#pragma unroll
    for (int i = 0; i < 4; i++) {
      GLD_LDS16(Ag + (size_t)(i * 32 + srow) * K + k0, &As[i * 2048 + tid * 8]);
      GLD_LDS16(Bg + (size_t)(i * 32 + srow) * K + k0, &Bs[i * 2048 + tid * 8]);
    }
    __syncthreads();  // compiler emits vmcnt(0) before s_barrier

#pragma unroll
    for (int kk = 0; kk < 2; kk++) {
      half8 a[4], b[4];
#pragma unroll
      for (int m = 0; m < 4; m++)
        a[m] = *(const half8*)&As[(wr + m * 16 + frow) * 64 + kk * 32 + fk];
#pragma unroll
      for (int n = 0; n < 4; n++)
        b[n] = *(const half8*)&Bs[(wc + n * 16 + frow) * 64 + kk * 32 + fk];
#pragma unroll
      for (int m = 0; m < 4; m++)
#pragma unroll
        for (int n = 0; n < 4; n++)
          acc[m][n] = __builtin_amdgcn_mfma_f32_16x16x32_f16(a[m], b[n],
                                                             acc[m][n], 0, 0, 0);
    }
    __syncthreads();
  }

  // epilogue: C/D layout col = lane&15, row = (lane>>4)*4 + reg
  const int r0 = (lane >> 4) * 4;
  const int c0 = lane & 15;
#pragma unroll
  for (int n = 0; n < 4; n++) {
    const int col = bcol + wc + n * 16 + c0;
    const float bv = bias[col];
#pragma unroll
    for (int m = 0; m < 4; m++) {
#pragma unroll
      for (int r = 0; r < 4; r++) {
        const int row = brow + wr + m * 16 + r0 + r;
        float v = acc[m][n][r] + bv;
        if (EPI == 1) v = 0.5f * tanhf(v);
        if (EPI == 2)
          ((float*)Cout)[(size_t)row * N + col] = v;
        else
          ((_Float16*)Cout)[(size_t)row * N + col] = (_Float16)v;
      }
    }
  }
}

// ---------------------------------------------------------------------------
extern "C" void kernel_launch(void* const* d_in, const int* in_sizes, int n_in,
                              void* d_out, int out_size, void* d_ws,
                              size_t ws_size, hipStream_t stream) {
  (void)in_sizes;
  (void)n_in;
  (void)out_size;
  (void)ws_size;

  const float* x = (const float*)d_in[0];        // [4096,1024]
  const float* W_embed = (const float*)d_in[1];  // [2048,1024]
  const float* b_embed = (const float*)d_in[2];  // [2048]
  const float* W_layers = (const float*)d_in[3]; // [3,2048,2048]
  const float* b_layers = (const float*)d_in[4]; // [3,2048]
  const float* W_head = (const float*)d_in[5];   // [1024,2048]
  const float* b_head = (const float*)d_in[6];   // [1024]

  const int B = 4096, I = 1024, H = 2048, O = 1024;

  // Workspace carve (all f16, 256B-aligned): ~72 MB total.
  char* w = (char*)d_ws;
  auto carve = [&](size_t bytes) {
    char* p = w;
    w += (bytes + 255) & ~(size_t)255;
    return p;
  };
  _Float16* xh = (_Float16*)carve((size_t)B * I * 2);
  _Float16* Weh = (_Float16*)carve((size_t)H * I * 2);
  _Float16* Wlh = (_Float16*)carve((size_t)3 * H * H * 2);
  _Float16* Whh = (_Float16*)carve((size_t)O * H * 2);
  _Float16* bufE = (_Float16*)carve((size_t)B * H * 2);
  _Float16* bufA = (_Float16*)carve((size_t)B * H * 2);

  // Convert inputs to f16
  cvt_f32_to_f16<<<1024, 256, 0, stream>>>(x, xh, (long)B * I);
  cvt_f32_to_f16<<<1024, 256, 0, stream>>>(W_embed, Weh, (long)H * I);
  cvt_f32_to_f16<<<2048, 256, 0, stream>>>(W_layers, Wlh, (long)3 * H * H);
  cvt_f32_to_f16<<<1024, 256, 0, stream>>>(W_head, Whh, (long)O * H);

  dim3 blk(256);
  // x_emb = x @ W_embed^T + b_embed            [B,H], f16
  gemm_bt<0><<<dim3(H / 128, B / 128), blk, 0, stream>>>(xh, Weh, b_embed,
                                                         bufE, B, H, I);
  // h0 = 0.5*tanh(x_emb @ W0^T + b0)           [B,H], f16
  gemm_bt<1><<<dim3(H / 128, B / 128), blk, 0, stream>>>(
      bufE, Wlh, b_layers, bufA, B, H, H);
  // h1 = 0.5*tanh(h0 @ W1^T + b1)              [B,H], f16
  gemm_bt<1><<<dim3(H / 128, B / 128), blk, 0, stream>>>(
      bufA, Wlh + (size_t)H * H, b_layers + H, bufE, B, H, H);
  // h2 = 0.5*tanh(h1 @ W2^T + b2)              [B,H], f16
  gemm_bt<1><<<dim3(H / 128, B / 128), blk, 0, stream>>>(
      bufE, Wlh + (size_t)2 * H * H, b_layers + 2 * H, bufA, B, H, H);
  // out = h2 @ W_head^T + b_head               [B,O], f32
  gemm_bt<2><<<dim3(O / 128, B / 128), blk, 0, stream>>>(
      bufA, Whh, b_head, d_out, B, O, H);
}